// Round 9
// baseline (723.758 us; speedup 1.0000x reference)
//
#include <hip/hip_runtime.h>

#define NN   25000
#define EE   400000
#define FIN  256
#define CC   32
#define AA   9
#define WN   288   // CC*AA
#define BB   8
#define HH   64
#define SS   4
#define FOUT 256
#define CH   80000 // edges per chunk (5 chunks); w_t buffer = 288*CH bf16 = 46 MB

typedef float f32x4 __attribute__((ext_vector_type(4)));
typedef short short8 __attribute__((ext_vector_type(8)));
typedef short short4v __attribute__((ext_vector_type(4)));

__device__ __forceinline__ float silu_f(float v){ return v / (1.0f + __expf(-v)); }

// round-to-nearest-even float -> bf16 bits
__device__ __forceinline__ unsigned short f2bf(float f){
  unsigned int u = __builtin_bit_cast(unsigned int, f);
  u += 0x7FFFu + ((u >> 16) & 1u);
  return (unsigned short)(u >> 16);
}
__device__ __forceinline__ float bf2f(unsigned short u){
  unsigned int v = ((unsigned int)u) << 16;
  return __builtin_bit_cast(float, v);
}

// ---------------- h = (x @ W1) * (1/sqrt(16)) : [N, 32] ----------------
__global__ __launch_bounds__(256) void k_h(const float* __restrict__ x,
                                           const float* __restrict__ W1,
                                           float* __restrict__ h){
  int gid = blockIdx.x * 256 + threadIdx.x;   // N*CC threads exactly
  int n = gid >> 5, c = gid & 31;
  const float* xr = x + (size_t)n * FIN;
  float acc = 0.f;
  #pragma unroll 8
  for (int f = 0; f < FIN; ++f) acc = fmaf(xr[f], W1[f * CC + c], acc);
  h[gid] = acc * 0.25f;
}

// ---------------- one-shot: Wm1 -> [64][32] k-pad bf16, Wm2^T bf16, Wm3^T bf16 ----------------
__global__ __launch_bounds__(256) void k_cvt(const float* __restrict__ Wm1,
                                             const float* __restrict__ Wm2,
                                             const float* __restrict__ Wm3,
                                             unsigned short* __restrict__ wm1t,
                                             unsigned short* __restrict__ wm2t,
                                             unsigned short* __restrict__ wm3t){
  int i = blockIdx.x * 256 + threadIdx.x;
  if (i < HH * 32){           // wm1t[n][k] = Wm1[k][n] for k<8 else 0
    int n = i >> 5, k = i & 31;
    wm1t[i] = (k < BB) ? f2bf(Wm1[k * HH + n]) : (unsigned short)0;
  }
  if (i < HH * HH){           // wm2t[n][k] = Wm2[k][n]
    int n = i >> 6, k = i & 63;
    wm2t[n * 64 + k] = f2bf(Wm2[k * HH + n]);
  }
  if (i < WN * HH){           // wm3t[n][k] = Wm3[k][n]
    int n = i >> 6, k = i & 63;
    wm3t[n * 64 + k] = f2bf(Wm3[k * WN + n]);
  }
}

// ---------------- one-shot: Wsc [1024 k][256 n] f32 -> wscb [256 n][1024 k] bf16 ----------------
__global__ __launch_bounds__(256) void k_cvtsc(const float* __restrict__ Wsc,
                                               unsigned short* __restrict__ wscb){
  __shared__ float tile[32][33];
  const int k0 = blockIdx.x * 32;
  const int n0 = blockIdx.y * 32;
  const int t = threadIdx.x;
  #pragma unroll
  for (int p = 0; p < 4; ++p){
    int idx = t + p * 256;
    int r = idx >> 5, c = idx & 31;       // r: k-offset, c: n-offset
    tile[r][c] = Wsc[(size_t)(k0 + r) * 256 + n0 + c];
  }
  __syncthreads();
  #pragma unroll
  for (int p = 0; p < 4; ++p){
    int idx = t + p * 256;
    int r = idx >> 5, c = idx & 31;       // r: n-offset, c: k-offset
    wscb[(size_t)(n0 + r) * 1024 + k0 + c] = f2bf(tile[c][r]);
  }
}

// ---------------- counting sort of edges by dst, fused data permutation ----------------
__global__ __launch_bounds__(256) void k_hist(const int* __restrict__ eidx,
                                              int* __restrict__ cnt){
  int e = blockIdx.x * 256 + threadIdx.x;
  if (e < EE) atomicAdd(&cnt[eidx[e]], 1);
}

__global__ __launch_bounds__(1024) void k_scan(const int* __restrict__ cnt,
                                               int* __restrict__ cur){
  __shared__ int part[1024];
  const int t = threadIdx.x;
  const int base = t * 25;                 // 1024*25 = 25600 >= NN
  int s = 0;
  for (int i = 0; i < 25; ++i){
    int idx = base + i;
    s += (idx < NN) ? cnt[idx] : 0;
  }
  part[t] = s;
  __syncthreads();
  for (int off = 1; off < 1024; off <<= 1){
    int v = (t >= off) ? part[t - off] : 0;
    __syncthreads();
    part[t] += v;
    __syncthreads();
  }
  int run = part[t] - s;                   // exclusive base for this thread
  for (int i = 0; i < 25; ++i){
    int idx = base + i;
    if (idx < NN){
      cur[idx] = run;
      run += cnt[idx];
    }
  }
}

// reads coalesced (e-order), writes scattered fire-and-forget (p-order)
__global__ __launch_bounds__(256) void k_scatter(const int* __restrict__ eidx,
                                                 const float* __restrict__ eemb,
                                                 const float* __restrict__ sh,
                                                 int* __restrict__ cur,
                                                 unsigned short* __restrict__ ee_p,
                                                 float* __restrict__ sh_p,
                                                 int* __restrict__ src_p,
                                                 int* __restrict__ dst_p){
  int e = blockIdx.x * 256 + threadIdx.x;
  if (e < EE){
    int d = eidx[e];
    int p = atomicAdd(&cur[d], 1);
    dst_p[p] = d;
    src_p[p] = eidx[EE + e];
    float4 v0 = *(const float4*)&eemb[(size_t)e * BB];
    float4 v1 = *(const float4*)&eemb[(size_t)e * BB + 4];
    unsigned short t[8] = {f2bf(v0.x), f2bf(v0.y), f2bf(v0.z), f2bf(v0.w),
                           f2bf(v1.x), f2bf(v1.y), f2bf(v1.z), f2bf(v1.w)};
    *(short8*)&ee_p[(size_t)p * BB] = *(short8*)t;
    #pragma unroll
    for (int a = 0; a < AA; ++a) sh_p[(size_t)p * AA + a] = sh[(size_t)e * AA + a];
  }
}

// ---------------- sc_out = (x ⊗ node_attrs) @ Wsc via bf16 MFMA ----------------
__global__ __launch_bounds__(256) void k_sc(const float* __restrict__ x,
                                            const float* __restrict__ na,
                                            const unsigned short* __restrict__ wscb,
                                            float* __restrict__ out){
  __shared__ __align__(16) unsigned short As[64][72];    // 9 KB, stride 144 B
  __shared__ __align__(16) unsigned short Bs[256][72];   // 36 KB
  const int tid = threadIdx.x;
  const int m0 = blockIdx.x * 64;
  const int sm = tid >> 2;          // staging row 0..63
  const int sq = tid & 3;           // staging k-quarter
  float4 nav = {0.f, 0.f, 0.f, 0.f};
  if (m0 + sm < NN) nav = *(const float4*)&na[(size_t)(m0 + sm) * SS];
  const float nf[4] = {nav.x, nav.y, nav.z, nav.w};
  const int lane = tid & 63, wv = tid >> 6;
  const int row = lane & 15, kg = lane >> 4;
  const f32x4 zf = {0.f, 0.f, 0.f, 0.f};
  f32x4 acc[16];
  #pragma unroll
  for (int i = 0; i < 16; ++i) acc[i] = zf;

  for (int kc = 0; kc < FIN * SS; kc += 64){
    __syncthreads();
    {
      float4 xv = {0.f, 0.f, 0.f, 0.f};
      int fc4 = (kc >> 2) + sq * 4;
      if (m0 + sm < NN) xv = *(const float4*)&x[(size_t)(m0 + sm) * FIN + fc4];
      float xf[4] = {xv.x, xv.y, xv.z, xv.w};
      unsigned short tmp[16];
      #pragma unroll
      for (int f = 0; f < 4; ++f)
        #pragma unroll
        for (int s = 0; s < 4; ++s) tmp[f * 4 + s] = f2bf(xf[f] * nf[s]);
      *(short8*)&As[sm][sq * 16]     = *(short8*)&tmp[0];
      *(short8*)&As[sm][sq * 16 + 8] = *(short8*)&tmp[8];
    }
    #pragma unroll
    for (int r = 0; r < 4; ++r){
      int ch = tid + r * 256;         // 0..1023
      int n = ch >> 2, c4 = ch & 3;
      const unsigned short* src = wscb + (size_t)n * 1024 + kc + c4 * 16;
      *(short8*)&Bs[n][c4 * 16]     = *(const short8*)src;
      *(short8*)&Bs[n][c4 * 16 + 8] = *(const short8*)(src + 8);
    }
    __syncthreads();
    #pragma unroll
    for (int ks = 0; ks < 2; ++ks){
      short8 af = *(const short8*)&As[wv * 16 + row][ks * 32 + kg * 8];
      #pragma unroll
      for (int nt = 0; nt < 16; ++nt){
        short8 bfr = *(const short8*)&Bs[nt * 16 + row][ks * 32 + kg * 8];
        acc[nt] = __builtin_amdgcn_mfma_f32_16x16x32_bf16(af, bfr, acc[nt], 0, 0, 0);
      }
    }
  }
  #pragma unroll
  for (int nt = 0; nt < 16; ++nt){
    #pragma unroll
    for (int r = 0; r < 4; ++r){
      int m = m0 + wv * 16 + kg * 4 + r;
      if (m < NN) out[(size_t)m * FOUT + nt * 16 + row] = acc[nt][r];
    }
  }
}

// ---------------- k_mlp: edge MLP (3x bf16 MFMA), barrier-free, per-wave 16 edges ----------------
// Writes raw TP weights transposed: w_t[j][e_local] bf16, j<288, e_local<CH.
// Lane holds (j fixed, 4 consecutive edges) -> one 8B store per nt. No __syncthreads.
__global__ __launch_bounds__(256) void k_mlp(const unsigned short* __restrict__ ee_p,   // chunk base
                                             const unsigned short* __restrict__ wm1t,
                                             const unsigned short* __restrict__ wm2t,
                                             const unsigned short* __restrict__ wm3t,
                                             unsigned short* __restrict__ w_t){
  __shared__ __align__(16) unsigned short t1b[64][72];   // 9 KB; wave-private 16-row slices; L2 aliases
  const int tid = threadIdx.x;

  // bijective XCD swizzle: nwg = CH/64 = 1250 = 8*156 + 2
  const int nwg = CH / 64;
  const int q = nwg >> 3, rr = nwg & 7;
  int bid = blockIdx.x;
  int xcd = bid & 7, li = bid >> 3;
  int swz = (xcd < rr ? xcd * (q + 1) : rr * (q + 1) + (xcd - rr) * q) + li;
  const int e0 = swz * 64;    // chunk-local edge base

  const int lane = tid & 63;
  const int wv   = tid >> 6;
  const int row  = lane & 15;
  const int kg   = lane >> 4;
  const f32x4 zf = {0.f, 0.f, 0.f, 0.f};

  // ---- layer 1 (MFMA, K=8 zero-padded to 32): t1 = silu(ee @ Wm1) ----
  {
    short8 a1 = {0, 0, 0, 0, 0, 0, 0, 0};
    if (kg == 0) a1 = *(const short8*)&ee_p[(size_t)(e0 + wv * 16 + row) * BB];
    #pragma unroll
    for (int nt = 0; nt < 4; ++nt){
      short8 b = *(const short8*)&wm1t[(nt * 16 + row) * 32 + kg * 8];
      f32x4 acc = __builtin_amdgcn_mfma_f32_16x16x32_bf16(a1, b, zf, 0, 0, 0);
      #pragma unroll
      for (int r = 0; r < 4; ++r)
        t1b[wv * 16 + kg * 4 + r][nt * 16 + row] = f2bf(silu_f(acc[r]));
    }
  }
  // no barrier: rows [16w,16w+16) wave-private

  // ---- layer 2 (MFMA): t2 = silu(t1 @ Wm2); written back into t1b (alias safe) ----
  {
    short8 a2k0 = *(const short8*)&t1b[wv * 16 + row][kg * 8];
    short8 a2k1 = *(const short8*)&t1b[wv * 16 + row][kg * 8 + 32];
    #pragma unroll
    for (int nt = 0; nt < 4; ++nt){
      const unsigned short* bp = wm2t + (size_t)((nt * 16 + row) * 64 + kg * 8);
      short8 b0 = *(const short8*)bp;
      short8 b1 = *(const short8*)(bp + 32);
      f32x4 acc = __builtin_amdgcn_mfma_f32_16x16x32_bf16(a2k0, b0, zf, 0, 0, 0);
      acc = __builtin_amdgcn_mfma_f32_16x16x32_bf16(a2k1, b1, acc, 0, 0, 0);
      #pragma unroll
      for (int r = 0; r < 4; ++r)
        t1b[wv * 16 + kg * 4 + r][nt * 16 + row] = f2bf(silu_f(acc[r]));
    }
  }

  // ---- layer 3 (MFMA): w = t2 @ Wm3 (no activation) -> w_t[j][e] bf16 ----
  {
    short8 a3k0 = *(const short8*)&t1b[wv * 16 + row][kg * 8];
    short8 a3k1 = *(const short8*)&t1b[wv * 16 + row][kg * 8 + 32];
    const int ebase = e0 + wv * 16 + kg * 4;
    const unsigned short* bp = wm3t + (size_t)(row * 64 + kg * 8);
    short8 b0n = *(const short8*)bp;
    short8 b1n = *(const short8*)(bp + 32);
    for (int nt = 0; nt < 18; ++nt){
      short8 b0 = b0n, b1 = b1n;
      if (nt < 17){
        const unsigned short* bp2 = wm3t + (size_t)(((nt + 1) * 16 + row) * 64 + kg * 8);
        b0n = *(const short8*)bp2;
        b1n = *(const short8*)(bp2 + 32);
      }
      f32x4 acc = __builtin_amdgcn_mfma_f32_16x16x32_bf16(a3k0, b0, zf, 0, 0, 0);
      acc = __builtin_amdgcn_mfma_f32_16x16x32_bf16(a3k1, b1, acc, 0, 0, 0);
      int j = nt * 16 + row;
      unsigned short pk[4];
      #pragma unroll
      for (int r = 0; r < 4; ++r) pk[r] = f2bf(acc[r]);
      *(short4v*)&w_t[(size_t)j * CH + ebase] = *(short4v*)pk;
    }
  }
}

// ---------------- k_tp: streaming TP + dst-segmented reduction ----------------
// Block = 64 dst-sorted edges, 256 threads. Thread owns column j (c,a_ constant),
// scans edges sequentially from registers; interior segments -> plain store,
// boundary segments -> atomicAdd. No LDS atomics.
__global__ __launch_bounds__(256) void k_tp(const unsigned short* __restrict__ w_t,
                                            const float* __restrict__ sh_p,    // chunk base
                                            const int* __restrict__ src_p,     // chunk base
                                            const int* __restrict__ dst_p,     // chunk base
                                            const float* __restrict__ h,
                                            float* __restrict__ agg){
  __shared__ float hs_s[64][36];    // 9 KB
  __shared__ float sh_s[64][13];    // 3.25 KB
  __shared__ int   dst_s[64];
  const int tid = threadIdx.x;

  // same bijective swizzle as k_mlp (k_tp block b reads what same-XCD k_mlp block b wrote)
  const int nwg = CH / 64;
  const int q = nwg >> 3, rr = nwg & 7;
  int bid = blockIdx.x;
  int xcd = bid & 7, li = bid >> 3;
  int swz = (xcd < rr ? xcd * (q + 1) : rr * (q + 1) + (xcd - rr) * q) + li;
  const int e0 = swz * 64;

  // ---- staging ----
  {
    int e = tid >> 2, c0 = (tid & 3) * 8;
    const float* hr = h + (size_t)src_p[e0 + e] * CC + c0;
    *(float4*)&hs_s[e][c0]     = *(const float4*)hr;
    *(float4*)&hs_s[e][c0 + 4] = *(const float4*)(hr + 4);
  }
  for (int i = tid; i < 64 * AA; i += 256){
    int e = i / 9, a = i - e * 9;
    sh_s[e][a] = sh_p[(size_t)e0 * AA + i];
  }
  if (tid < 64) dst_s[tid] = dst_p[e0 + tid];
  __syncthreads();

  for (int j = tid; j < WN; j += 256){
    const int c  = j / 9;
    const int a_ = j - 9 * c;
    const unsigned short* wp = w_t + (size_t)j * CH + e0;
    float acc = 0.f;
    int d = dst_s[0];
    int seg_start = 0;
    #pragma unroll
    for (int eb = 0; eb < 8; ++eb){
      short8 w8 = *(const short8*)&wp[eb * 8];
      #pragma unroll
      for (int ei = 0; ei < 8; ++ei){
        int e = eb * 8 + ei;
        int de = dst_s[e];
        if (de != d){
          if (seg_start > 0) agg[(size_t)d * WN + j] = acc;        // interior: exclusive
          else atomicAdd(&agg[(size_t)d * WN + j], acc);           // first: may straddle
          d = de; acc = 0.f; seg_start = e;
        }
        float w = bf2f((unsigned short)w8[ei]);
        acc = fmaf(w * hs_s[e][c], sh_s[e][a_], acc);
      }
    }
    atomicAdd(&agg[(size_t)d * WN + j], acc);                      // last: may straddle
  }
}

// ---------------- out = silu(agg @ W2) + sc_out ----------------
__global__ __launch_bounds__(256) void k_out(const float* __restrict__ agg,
                                             const float* __restrict__ W2,
                                             float* __restrict__ out){
  __shared__ float As[32][68];   // padded: float4-aligned rows, spread banks
  __shared__ float Bs[32][64];
  const int row0 = blockIdx.x * 64;
  const int col0 = blockIdx.y * 64;
  const int tid = threadIdx.x;
  const int tm = tid >> 4, tn = tid & 15;
  float acc[4][4] = {};
  for (int kc = 0; kc < WN; kc += 32){
    #pragma unroll
    for (int t = 0; t < 8; ++t){
      int idx = tid + t * 256;
      int m = idx >> 5, kk = idx & 31;    // lanes along k: contiguous 128 B from agg
      int n = row0 + m;
      float v = 0.f;
      if (n < NN) v = agg[(size_t)n * WN + kc + kk];
      As[kk][m] = v;
    }
    #pragma unroll
    for (int t = 0; t < 8; ++t){
      int idx = tid + t * 256;
      int o = idx & 63, kk = idx >> 6;
      Bs[kk][o] = W2[(size_t)(kc + kk) * FOUT + col0 + o];
    }
    __syncthreads();
    #pragma unroll
    for (int kk = 0; kk < 32; ++kk){
      float4 av = *(const float4*)&As[kk][tm * 4];
      float4 bv = *(const float4*)&Bs[kk][tn * 4];
      float a[4] = {av.x, av.y, av.z, av.w};
      float b[4] = {bv.x, bv.y, bv.z, bv.w};
      #pragma unroll
      for (int i = 0; i < 4; ++i)
        #pragma unroll
        for (int j = 0; j < 4; ++j)
          acc[i][j] = fmaf(a[i], b[j], acc[i][j]);
    }
    __syncthreads();
  }
  #pragma unroll
  for (int i = 0; i < 4; ++i){
    int n = row0 + tm * 4 + i;
    if (n < NN){
      float4 sc = *(const float4*)&out[(size_t)n * FOUT + col0 + tn * 4];
      float4 v;
      v.x = silu_f(acc[i][0]) + sc.x;
      v.y = silu_f(acc[i][1]) + sc.y;
      v.z = silu_f(acc[i][2]) + sc.z;
      v.w = silu_f(acc[i][3]) + sc.w;
      *(float4*)&out[(size_t)n * FOUT + col0 + tn * 4] = v;
    }
  }
}

extern "C" void kernel_launch(void* const* d_in, const int* in_sizes, int n_in,
                              void* d_out, int out_size, void* d_ws, size_t ws_size,
                              hipStream_t stream){
  const float* x    = (const float*)d_in[0];
  const float* na   = (const float*)d_in[1];
  const float* eemb = (const float*)d_in[2];
  const float* shp  = (const float*)d_in[3];
  const int*   eidx = (const int*)d_in[4];
  const float* W1   = (const float*)d_in[5];
  const float* Wm1  = (const float*)d_in[6];
  const float* Wm2  = (const float*)d_in[7];
  const float* Wm3  = (const float*)d_in[8];
  const float* W2   = (const float*)d_in[9];
  const float* Wsc  = (const float*)d_in[10];
  float* out  = (float*)d_out;

  float* agg  = (float*)d_ws;                        // [N,288] f32   28.8 MB
  float* hbuf = agg + (size_t)NN * WN;               // [N,32] f32     3.2 MB
  float* sh_p = hbuf + (size_t)NN * CC;              // [E,9] f32     14.4 MB
  int*   cnt  = (int*)(sh_p + (size_t)EE * AA);      // [N]
  int*   cur  = cnt + NN;                            // [N]
  int*   src_p = cur + NN;                           // [E]
  int*   dst_p = src_p + EE;                         // [E]
  unsigned short* ee_p = (unsigned short*)(dst_p + EE);  // [E,8] bf16  6.4 MB
  unsigned short* wm1t = ee_p + (size_t)EE * BB;         // [64,32]
  unsigned short* wm2t = wm1t + HH * 32;                 // [64,64]
  unsigned short* wm3t = wm2t + HH * HH;                 // [288,64]
  unsigned short* wscb = wm3t + WN * HH;                 // [256,1024]
  unsigned short* w_t  = wscb + 256 * 1024;              // [288,CH] bf16 46 MB (chunk-reused)

  hipMemsetAsync(agg, 0, (size_t)NN * WN * sizeof(float), stream);
  hipMemsetAsync(cnt, 0, (size_t)NN * sizeof(int), stream);
  k_cvt    <<<dim3((WN * HH + 255) / 256), dim3(256), 0, stream>>>(Wm1, Wm2, Wm3, wm1t, wm2t, wm3t);
  k_cvtsc  <<<dim3(32, 8), dim3(256), 0, stream>>>(Wsc, wscb);
  k_hist   <<<dim3((EE + 255) / 256), dim3(256),  0, stream>>>(eidx, cnt);
  k_scan   <<<dim3(1),                dim3(1024), 0, stream>>>(cnt, cur);
  k_scatter<<<dim3((EE + 255) / 256), dim3(256),  0, stream>>>(eidx, eemb, shp, cur,
                                                               ee_p, sh_p, src_p, dst_p);
  k_h  <<<dim3(NN * CC / 256), dim3(256), 0, stream>>>(x, W1, hbuf);
  k_sc <<<dim3((NN + 63) / 64), dim3(256), 0, stream>>>(x, na, wscb, out);
  for (int c = 0; c < EE / CH; ++c){
    k_mlp<<<dim3(CH / 64), dim3(256), 0, stream>>>(ee_p + (size_t)c * CH * BB,
                                                   wm1t, wm2t, wm3t, w_t);
    k_tp <<<dim3(CH / 64), dim3(256), 0, stream>>>(w_t,
                                                   sh_p + (size_t)c * CH * AA,
                                                   src_p + (size_t)c * CH,
                                                   dst_p + (size_t)c * CH,
                                                   hbuf, agg);
  }
  k_out<<<dim3((NN + 63) / 64, FOUT / 64), dim3(256), 0, stream>>>(agg, W2, out);
}

// Round 11
// 573.382 us; speedup vs baseline: 1.2623x; 1.2623x over previous
//
#include <hip/hip_runtime.h>

#define NN   25000
#define EE   400000
#define FIN  256
#define CC   32
#define AA   9
#define WN   288   // CC*AA
#define BB   8
#define HH   64
#define SS   4
#define FOUT 256
#define EPB  64    // edges per block in k_edge (4 waves)
#define NSEG 10    // max LDS segments per block

typedef float f32x4 __attribute__((ext_vector_type(4)));
typedef short short8 __attribute__((ext_vector_type(8)));

__device__ __forceinline__ float silu_f(float v){ return v / (1.0f + __expf(-v)); }

// round-to-nearest-even float -> bf16 bits
__device__ __forceinline__ unsigned short f2bf(float f){
  unsigned int u = __builtin_bit_cast(unsigned int, f);
  u += 0x7FFFu + ((u >> 16) & 1u);
  return (unsigned short)(u >> 16);
}

// ---------------- h = (x @ W1) * (1/sqrt(16)) : [N, 32] ----------------
__global__ __launch_bounds__(256) void k_h(const float* __restrict__ x,
                                           const float* __restrict__ W1,
                                           float* __restrict__ h){
  int gid = blockIdx.x * 256 + threadIdx.x;   // N*CC threads exactly
  int n = gid >> 5, c = gid & 31;
  const float* xr = x + (size_t)n * FIN;
  float acc = 0.f;
  #pragma unroll 8
  for (int f = 0; f < FIN; ++f) acc = fmaf(xr[f], W1[f * CC + c], acc);
  h[gid] = acc * 0.25f;
}

// ---------------- one-shot: Wm1 -> [64][32] k-pad bf16, Wm2^T bf16, Wm3^T bf16 ----------------
__global__ __launch_bounds__(256) void k_cvt(const float* __restrict__ Wm1,
                                             const float* __restrict__ Wm2,
                                             const float* __restrict__ Wm3,
                                             unsigned short* __restrict__ wm1t,
                                             unsigned short* __restrict__ wm2t,
                                             unsigned short* __restrict__ wm3t){
  int i = blockIdx.x * 256 + threadIdx.x;
  if (i < HH * 32){           // wm1t[n][k] = Wm1[k][n] for k<8 else 0
    int n = i >> 5, k = i & 31;
    wm1t[i] = (k < BB) ? f2bf(Wm1[k * HH + n]) : (unsigned short)0;
  }
  if (i < HH * HH){           // wm2t[n][k] = Wm2[k][n]
    int n = i >> 6, k = i & 63;
    wm2t[n * 64 + k] = f2bf(Wm2[k * HH + n]);
  }
  if (i < WN * HH){           // wm3t[n][k] = Wm3[k][n]
    int n = i >> 6, k = i & 63;
    wm3t[n * 64 + k] = f2bf(Wm3[k * WN + n]);
  }
}

// ---------------- one-shot: Wsc [1024 k][256 n] f32 -> wscb [256 n][1024 k] bf16 ----------------
__global__ __launch_bounds__(256) void k_cvtsc(const float* __restrict__ Wsc,
                                               unsigned short* __restrict__ wscb){
  __shared__ float tile[32][33];
  const int k0 = blockIdx.x * 32;
  const int n0 = blockIdx.y * 32;
  const int t = threadIdx.x;
  #pragma unroll
  for (int p = 0; p < 4; ++p){
    int idx = t + p * 256;
    int r = idx >> 5, c = idx & 31;       // r: k-offset, c: n-offset
    tile[r][c] = Wsc[(size_t)(k0 + r) * 256 + n0 + c];
  }
  __syncthreads();
  #pragma unroll
  for (int p = 0; p < 4; ++p){
    int idx = t + p * 256;
    int r = idx >> 5, c = idx & 31;       // r: n-offset, c: k-offset
    wscb[(size_t)(n0 + r) * 1024 + k0 + c] = f2bf(tile[c][r]);
  }
}

// ---------------- counting sort of edges by dst, fused data permutation ----------------
__global__ __launch_bounds__(256) void k_hist(const int* __restrict__ eidx,
                                              int* __restrict__ cnt){
  int e = blockIdx.x * 256 + threadIdx.x;
  if (e < EE) atomicAdd(&cnt[eidx[e]], 1);
}

__global__ __launch_bounds__(1024) void k_scan(const int* __restrict__ cnt,
                                               int* __restrict__ cur){
  __shared__ int part[1024];
  const int t = threadIdx.x;
  const int base = t * 25;                 // 1024*25 = 25600 >= NN
  int s = 0;
  for (int i = 0; i < 25; ++i){
    int idx = base + i;
    s += (idx < NN) ? cnt[idx] : 0;
  }
  part[t] = s;
  __syncthreads();
  for (int off = 1; off < 1024; off <<= 1){
    int v = (t >= off) ? part[t - off] : 0;
    __syncthreads();
    part[t] += v;
    __syncthreads();
  }
  int run = part[t] - s;                   // exclusive base for this thread
  for (int i = 0; i < 25; ++i){
    int idx = base + i;
    if (idx < NN){
      cur[idx] = run;
      run += cnt[idx];
    }
  }
}

// reads coalesced (e-order), writes scattered fire-and-forget (p-order)
__global__ __launch_bounds__(256) void k_scatter(const int* __restrict__ eidx,
                                                 const float* __restrict__ eemb,
                                                 const float* __restrict__ sh,
                                                 int* __restrict__ cur,
                                                 unsigned short* __restrict__ ee_p,
                                                 float* __restrict__ sh_p,
                                                 int* __restrict__ src_p,
                                                 int* __restrict__ dst_p){
  int e = blockIdx.x * 256 + threadIdx.x;
  if (e < EE){
    int d = eidx[e];
    int p = atomicAdd(&cur[d], 1);
    dst_p[p] = d;
    src_p[p] = eidx[EE + e];
    float4 v0 = *(const float4*)&eemb[(size_t)e * BB];
    float4 v1 = *(const float4*)&eemb[(size_t)e * BB + 4];
    unsigned short t[8] = {f2bf(v0.x), f2bf(v0.y), f2bf(v0.z), f2bf(v0.w),
                           f2bf(v1.x), f2bf(v1.y), f2bf(v1.z), f2bf(v1.w)};
    *(short8*)&ee_p[(size_t)p * BB] = *(short8*)t;
    #pragma unroll
    for (int a = 0; a < AA; ++a) sh_p[(size_t)p * AA + a] = sh[(size_t)e * AA + a];
  }
}

// ---------------- sc_out = (x ⊗ node_attrs) @ Wsc via bf16 MFMA ----------------
__global__ __launch_bounds__(256) void k_sc(const float* __restrict__ x,
                                            const float* __restrict__ na,
                                            const unsigned short* __restrict__ wscb,
                                            float* __restrict__ out){
  __shared__ __align__(16) unsigned short As[64][72];    // 9 KB, stride 144 B
  __shared__ __align__(16) unsigned short Bs[256][72];   // 36 KB
  const int tid = threadIdx.x;
  const int m0 = blockIdx.x * 64;
  const int sm = tid >> 2;          // staging row 0..63
  const int sq = tid & 3;           // staging k-quarter
  float4 nav = {0.f, 0.f, 0.f, 0.f};
  if (m0 + sm < NN) nav = *(const float4*)&na[(size_t)(m0 + sm) * SS];
  const float nf[4] = {nav.x, nav.y, nav.z, nav.w};
  const int lane = tid & 63, wv = tid >> 6;
  const int row = lane & 15, kg = lane >> 4;
  const f32x4 zf = {0.f, 0.f, 0.f, 0.f};
  f32x4 acc[16];
  #pragma unroll
  for (int i = 0; i < 16; ++i) acc[i] = zf;

  for (int kc = 0; kc < FIN * SS; kc += 64){
    __syncthreads();
    {
      float4 xv = {0.f, 0.f, 0.f, 0.f};
      int fc4 = (kc >> 2) + sq * 4;
      if (m0 + sm < NN) xv = *(const float4*)&x[(size_t)(m0 + sm) * FIN + fc4];
      float xf[4] = {xv.x, xv.y, xv.z, xv.w};
      unsigned short tmp[16];
      #pragma unroll
      for (int f = 0; f < 4; ++f)
        #pragma unroll
        for (int s = 0; s < 4; ++s) tmp[f * 4 + s] = f2bf(xf[f] * nf[s]);
      *(short8*)&As[sm][sq * 16]     = *(short8*)&tmp[0];
      *(short8*)&As[sm][sq * 16 + 8] = *(short8*)&tmp[8];
    }
    #pragma unroll
    for (int r = 0; r < 4; ++r){
      int ch = tid + r * 256;         // 0..1023
      int n = ch >> 2, c4 = ch & 3;
      const unsigned short* src = wscb + (size_t)n * 1024 + kc + c4 * 16;
      *(short8*)&Bs[n][c4 * 16]     = *(const short8*)src;
      *(short8*)&Bs[n][c4 * 16 + 8] = *(const short8*)(src + 8);
    }
    __syncthreads();
    #pragma unroll
    for (int ks = 0; ks < 2; ++ks){
      short8 af = *(const short8*)&As[wv * 16 + row][ks * 32 + kg * 8];
      #pragma unroll
      for (int nt = 0; nt < 16; ++nt){
        short8 bfr = *(const short8*)&Bs[nt * 16 + row][ks * 32 + kg * 8];
        acc[nt] = __builtin_amdgcn_mfma_f32_16x16x32_bf16(af, bfr, acc[nt], 0, 0, 0);
      }
    }
  }
  #pragma unroll
  for (int nt = 0; nt < 16; ++nt){
    #pragma unroll
    for (int r = 0; r < 4; ++r){
      int m = m0 + wv * 16 + kg * 4 + r;
      if (m < NN) out[(size_t)m * FOUT + nt * 16 + row] = acc[nt][r];
    }
  }
}

// ---------------- fused edge MLP (3x bf16 MFMA) + TP + LDS segmented reduce ----------------
// 64 dst-sorted edges per block, 4 waves; wave w owns edges [16w,16w+16).
// t2b aliases t1b; agg_s aliases both. hs/sh in broadcast-friendly [e][stride]
// layouts. 3 barriers total; staging latency hides under L1/L2 MFMA.
__global__ __launch_bounds__(256) void k_edge(const unsigned short* __restrict__ ee_p,
                                              const float* __restrict__ sh_p,
                                              const int* __restrict__ src_p,
                                              const int* __restrict__ dst_p,
                                              const float* __restrict__ h,
                                              const unsigned short* __restrict__ wm1t,
                                              const unsigned short* __restrict__ wm2t,
                                              const unsigned short* __restrict__ wm3t,
                                              float* __restrict__ agg){
  __shared__ float hs_s[EPB][36];                        // 9 KB  (2-way max on write)
  __shared__ float sh_s[EPB][13];                        // 3.25 KB
  __shared__ __align__(16) char scratch[NSEG * WN * 4];  // 11.25 KB: t1b (t2b aliases) / agg_s
  __shared__ int   dst_s[EPB];
  __shared__ unsigned char dloc_s[EPB];
  __shared__ unsigned char firstE_s[NSEG];
  __shared__ int   nD_s;
  unsigned short (*t1b)[72] = (unsigned short(*)[72])scratch;   // [64][72] u16 = 9216 B
  unsigned short (*t2b)[72] = t1b;                              // alias (safe: per-wave slices)
  float (*agg_s)[WN] = (float(*)[WN])scratch;                   // [NSEG][288]
  const int tid = threadIdx.x;

  // bijective XCD swizzle: nwg = 6250 = 8*781 + 2
  const int nwg = EE / EPB;
  const int q = nwg >> 3, rr = nwg & 7;
  int bid = blockIdx.x;
  int xcd = bid & 7, li = bid >> 3;
  int swz = (xcd < rr ? xcd * (q + 1) : rr * (q + 1) + (xcd - rr) * q) + li;
  const int e0 = swz * EPB;

  // ---- staging (issued first; latency hides under L1/L2 below) ----
  {
    int e = tid >> 2, c0 = (tid & 3) * 8;
    const float* hr = h + (size_t)src_p[e0 + e] * CC + c0;
    *(float4*)&hs_s[e][c0]     = *(const float4*)hr;
    *(float4*)&hs_s[e][c0 + 4] = *(const float4*)(hr + 4);
  }
  for (int i = tid; i < EPB * AA; i += 256){
    int e = i / 9, a = i - e * 9;
    sh_s[e][a] = sh_p[(size_t)e0 * AA + i];
  }
  if (tid < NSEG) firstE_s[tid] = 0;
  if (tid < EPB){   // wave 0: dst, boundary flags, segment index via ballot
    int d = dst_p[e0 + tid];
    dst_s[tid] = d;
    bool bnd = (tid > 0) && (d != dst_p[e0 + tid - 1]);
    unsigned long long m = __ballot(bnd);
    int dl = __popcll(m & ((2ull << tid) - 1ull));   // includes own bit
    dloc_s[tid] = (unsigned char)dl;
    if (bnd && dl < NSEG) firstE_s[dl] = (unsigned char)tid;
    if (tid == EPB - 1) nD_s = dl + 1;
  }

  const int lane = tid & 63;
  const int wv   = tid >> 6;
  const int row  = lane & 15;
  const int kg   = lane >> 4;
  const f32x4 zf = {0.f, 0.f, 0.f, 0.f};

  // ---- layer 1 (MFMA, K=8 zero-padded to 32): t1 = silu(ee @ Wm1) ----
  {
    short8 a1 = {0, 0, 0, 0, 0, 0, 0, 0};
    if (kg == 0) a1 = *(const short8*)&ee_p[(size_t)(e0 + wv * 16 + row) * BB];
    #pragma unroll
    for (int nt = 0; nt < 4; ++nt){
      short8 b = *(const short8*)&wm1t[(nt * 16 + row) * 32 + kg * 8];
      f32x4 acc = __builtin_amdgcn_mfma_f32_16x16x32_bf16(a1, b, zf, 0, 0, 0);
      #pragma unroll
      for (int r = 0; r < 4; ++r)
        t1b[wv * 16 + kg * 4 + r][nt * 16 + row] = f2bf(silu_f(acc[r]));
    }
  }
  // no barrier: t1b rows [16w,16w+16) written and read by wave w only

  // ---- layer 2 (MFMA): t2 = silu(t1 @ Wm2); t2b aliases t1b ----
  {
    short8 a2k0 = *(const short8*)&t1b[wv * 16 + row][kg * 8];
    short8 a2k1 = *(const short8*)&t1b[wv * 16 + row][kg * 8 + 32];
    #pragma unroll
    for (int nt = 0; nt < 4; ++nt){
      const unsigned short* bp = wm2t + (size_t)((nt * 16 + row) * 64 + kg * 8);
      short8 b0 = *(const short8*)bp;
      short8 b1 = *(const short8*)(bp + 32);
      f32x4 acc = __builtin_amdgcn_mfma_f32_16x16x32_bf16(a2k0, b0, zf, 0, 0, 0);
      acc = __builtin_amdgcn_mfma_f32_16x16x32_bf16(a2k1, b1, acc, 0, 0, 0);
      #pragma unroll
      for (int r = 0; r < 4; ++r)
        t2b[wv * 16 + kg * 4 + r][nt * 16 + row] = f2bf(silu_f(acc[r]));
    }
  }

  // ---- layer 3 (MFMA) + TP + segmented reduce ----
  {
    short8 a3k0 = *(const short8*)&t2b[wv * 16 + row][kg * 8];
    short8 a3k1 = *(const short8*)&t2b[wv * 16 + row][kg * 8 + 32];
    const int ebase = wv * 16 + kg * 4;

    __syncthreads();   // staging visible; all waves done reading t2b (scratch reusable)

    int dl[4], d[4];
    #pragma unroll
    for (int r = 0; r < 4; ++r){ dl[r] = dloc_s[ebase + r]; d[r] = dst_s[ebase + r]; }
    const int nD = nD_s;
    const bool direct = (nD > NSEG);     // rare: fall back to global atomics
    if (!direct){
      for (int i = tid; i < nD * WN; i += 256) ((float*)agg_s)[i] = 0.f;
    }
    __syncthreads();

    // incremental j = c*9 + a_ decomposition (j = nt*16 + row)
    int c  = (row >= 9) ? 1 : 0;
    int a_ = row - 9 * c;
    // register double-buffer of wm3t B fragments
    const unsigned short* bp = wm3t + (size_t)(row * 64 + kg * 8);
    short8 b0n = *(const short8*)bp;
    short8 b1n = *(const short8*)(bp + 32);
    for (int nt = 0; nt < 18; ++nt){
      short8 b0 = b0n, b1 = b1n;
      if (nt < 17){
        const unsigned short* bp2 = wm3t + (size_t)(((nt + 1) * 16 + row) * 64 + kg * 8);
        b0n = *(const short8*)bp2;
        b1n = *(const short8*)(bp2 + 32);
      }
      f32x4 acc = __builtin_amdgcn_mfma_f32_16x16x32_bf16(a3k0, b0, zf, 0, 0, 0);
      acc = __builtin_amdgcn_mfma_f32_16x16x32_bf16(a3k1, b1, acc, 0, 0, 0);
      int j = nt * 16 + row;
      float vals[4];
      #pragma unroll
      for (int r = 0; r < 4; ++r)
        vals[r] = acc[r] * hs_s[ebase + r][c] * sh_s[ebase + r][a_];   // broadcast reads
      #pragma unroll
      for (int r = 0; r < 4; ++r){
        bool last = (r == 3) || (dl[r + 1] != dl[r]);
        if (!last){
          vals[r + 1] += vals[r];
        } else if (direct){
          atomicAdd(&agg[(size_t)d[r] * WN + j], vals[r]);
        } else {
          atomicAdd(&agg_s[dl[r]][j], vals[r]);
        }
      }
      a_ += 7; c += 1;
      if (a_ >= 9){ a_ -= 9; c += 1; }
    }

    __syncthreads();
    if (!direct){
      // interior segments: exclusively owned -> plain store.
      // boundary segments (first/last): shared with neighbor blocks -> atomic.
      for (int l = 0; l < nD; ++l){
        int dd = dst_s[firstE_s[l]];
        float* dstp = &agg[(size_t)dd * WN];
        if (l > 0 && l < nD - 1){
          for (int j = tid; j < WN; j += 256) dstp[j] = agg_s[l][j];
        } else {
          for (int j = tid; j < WN; j += 256) atomicAdd(&dstp[j], agg_s[l][j]);
        }
      }
    }
  }
}

// ---------------- out = silu(agg @ W2) + sc_out ----------------
// Single pass: BM=64, BN=256 (agg read exactly once). Thread owns columns
// tn*4 + q*64 (strided -> Bs b128 reads land on 64 consecutive banks, 2-way max).
__global__ __launch_bounds__(256) void k_out(const float* __restrict__ agg,
                                             const float* __restrict__ W2,
                                             float* __restrict__ out){
  __shared__ float As[32][68];    // 8.5 KB, rows 272 B (16B-aligned)
  __shared__ float Bs[32][256];   // 32 KB
  const int row0 = blockIdx.x * 64;
  const int tid = threadIdx.x;
  const int tm = tid >> 4, tn = tid & 15;
  float acc[4][16] = {};
  for (int kc = 0; kc < WN; kc += 32){
    #pragma unroll
    for (int t = 0; t < 8; ++t){
      int idx = tid + t * 256;
      int m = idx >> 5, kk = idx & 31;    // lanes along k: contiguous 128 B from agg
      int n = row0 + m;
      float v = 0.f;
      if (n < NN) v = agg[(size_t)n * WN + kc + kk];
      As[kk][m] = v;
    }
    // stage all 32x256 of Bs: thread -> one float4 per iter, 8 iters = 8192 floats
    #pragma unroll
    for (int t = 0; t < 8; ++t){
      int ch = tid + t * 256;             // 0..2047
      int kk = ch >> 6, c4 = (ch & 63) * 4;   // kk 0..31, c4 0..252
      *(float4*)&Bs[kk][c4] = *(const float4*)&W2[(size_t)(kc + kk) * FOUT + c4];
    }
    __syncthreads();
    #pragma unroll
    for (int kk = 0; kk < 32; ++kk){
      float4 av = *(const float4*)&As[kk][tm * 4];
      float a[4] = {av.x, av.y, av.z, av.w};
      float b[16];
      #pragma unroll
      for (int qq = 0; qq < 4; ++qq)
        *(float4*)&b[qq * 4] = *(const float4*)&Bs[kk][tn * 4 + qq * 64];
      #pragma unroll
      for (int i = 0; i < 4; ++i)
        #pragma unroll
        for (int j = 0; j < 16; ++j)
          acc[i][j] = fmaf(a[i], b[j], acc[i][j]);
    }
    __syncthreads();
  }
  #pragma unroll
  for (int i = 0; i < 4; ++i){
    int n = row0 + tm * 4 + i;
    if (n < NN){
      #pragma unroll
      for (int qq = 0; qq < 4; ++qq){
        int col = tn * 4 + qq * 64;
        float4 sc = *(const float4*)&out[(size_t)n * FOUT + col];
        float4 v;
        v.x = silu_f(acc[i][qq * 4 + 0]) + sc.x;
        v.y = silu_f(acc[i][qq * 4 + 1]) + sc.y;
        v.z = silu_f(acc[i][qq * 4 + 2]) + sc.z;
        v.w = silu_f(acc[i][qq * 4 + 3]) + sc.w;
        *(float4*)&out[(size_t)n * FOUT + col] = v;
      }
    }
  }
}

extern "C" void kernel_launch(void* const* d_in, const int* in_sizes, int n_in,
                              void* d_out, int out_size, void* d_ws, size_t ws_size,
                              hipStream_t stream){
  const float* x    = (const float*)d_in[0];
  const float* na   = (const float*)d_in[1];
  const float* eemb = (const float*)d_in[2];
  const float* shp  = (const float*)d_in[3];
  const int*   eidx = (const int*)d_in[4];
  const float* W1   = (const float*)d_in[5];
  const float* Wm1  = (const float*)d_in[6];
  const float* Wm2  = (const float*)d_in[7];
  const float* Wm3  = (const float*)d_in[8];
  const float* W2   = (const float*)d_in[9];
  const float* Wsc  = (const float*)d_in[10];
  float* out  = (float*)d_out;

  float* agg  = (float*)d_ws;                        // [N,288] f32   28.8 MB
  float* hbuf = agg + (size_t)NN * WN;               // [N,32] f32     3.2 MB
  float* sh_p = hbuf + (size_t)NN * CC;              // [E,9] f32     14.4 MB
  int*   cnt  = (int*)(sh_p + (size_t)EE * AA);      // [N]
  int*   cur  = cnt + NN;                            // [N]
  int*   src_p = cur + NN;                           // [E]
  int*   dst_p = src_p + EE;                         // [E]
  unsigned short* ee_p = (unsigned short*)(dst_p + EE);  // [E,8] bf16  6.4 MB
  unsigned short* wm1t = ee_p + (size_t)EE * BB;         // [64,32]
  unsigned short* wm2t = wm1t + HH * 32;                 // [64,64]
  unsigned short* wm3t = wm2t + HH * HH;                 // [288,64]
  unsigned short* wscb = wm3t + WN * HH;                 // [256,1024]

  hipMemsetAsync(agg, 0, (size_t)NN * WN * sizeof(float), stream);
  hipMemsetAsync(cnt, 0, (size_t)NN * sizeof(int), stream);
  k_cvt    <<<dim3((WN * HH + 255) / 256), dim3(256), 0, stream>>>(Wm1, Wm2, Wm3, wm1t, wm2t, wm3t);
  k_cvtsc  <<<dim3(32, 8), dim3(256), 0, stream>>>(Wsc, wscb);
  k_hist   <<<dim3((EE + 255) / 256), dim3(256),  0, stream>>>(eidx, cnt);
  k_scan   <<<dim3(1),                dim3(1024), 0, stream>>>(cnt, cur);
  k_scatter<<<dim3((EE + 255) / 256), dim3(256),  0, stream>>>(eidx, eemb, shp, cur,
                                                               ee_p, sh_p, src_p, dst_p);
  k_h  <<<dim3(NN * CC / 256), dim3(256), 0, stream>>>(x, W1, hbuf);
  k_sc <<<dim3((NN + 63) / 64), dim3(256), 0, stream>>>(x, na, wscb, out);
  k_edge<<<dim3(EE / EPB), dim3(256), 0, stream>>>(ee_p, sh_p, src_p, dst_p, hbuf,
                                                   wm1t, wm2t, wm3t, agg);
  k_out<<<dim3((NN + 63) / 64), dim3(256), 0, stream>>>(agg, W2, out);
}